// Round 1
// baseline (557.911 us; speedup 1.0000x reference)
//
#include <hip/hip_runtime.h>

#define T 256
#define DT 0.05f
#define WHEELBASE 2.7f
#define MAX_STEER 0.5235987755982988f  // deg2rad(30)
#define MAX_SPEED 100.0f
#define FR 0.1f
#define FA 0.01f

// One thread per vehicle. Sequential over 256 time positions in groups of 4:
// group k stores states at positions 4k..4k+3 (state BEFORE ctrl[4k+j] is
// applied), so all loads/stores are aligned float4. The final computed state
// (position 256) is discarded, matching the reference's unused last control.
__global__ __launch_bounds__(256) void bicycle_kernel(
    const float* __restrict__ sx, const float* __restrict__ sy,
    const float* __restrict__ syaw, const float* __restrict__ ssp,
    const float* __restrict__ accel, const float* __restrict__ steering,
    float* __restrict__ out, int B)
{
    int b = blockIdx.x * blockDim.x + threadIdx.x;
    if (b >= B) return;

    float x   = sx[b];
    float y   = sy[b];
    float yaw = syaw[b];
    float sp  = ssp[b];

    const float4* a4 = (const float4*)(accel    + (size_t)b * T);
    const float4* s4 = (const float4*)(steering + (size_t)b * T);

    size_t plane = (size_t)B * T;
    float* ox = out + (size_t)b * T;
    float* oy = ox + plane;
    float* ow = oy + plane;
    float* os = ow + plane;

    #pragma unroll 4
    for (int k = 0; k < T / 4; ++k) {
        float4 av = a4[k];
        float4 sv = s4[k];
        float ac[4] = {av.x, av.y, av.z, av.w};
        float sc[4] = {sv.x, sv.y, sv.z, sv.w};

        float outx[4], outy[4], outw[4], outs[4];

        #pragma unroll
        for (int j = 0; j < 4; ++j) {
            // record state at position 4k+j
            outx[j] = x; outy[j] = y; outw[j] = yaw; outs[j] = sp;

            // advance one step using ctrl[4k+j]
            float fr   = fmaf(FA * sp, sp, sp * FR);          // 0.1*sp + 0.01*sp^2
            float spn  = fmaf(DT, ac[j] - fr, sp);
            spn        = fminf(fmaxf(spn, 0.0f), MAX_SPEED);
            float steer= fminf(fmaxf(sc[j], -MAX_STEER), MAX_STEER);
            float angv = sp * __tanf(steer) * (1.0f / WHEELBASE);
            float s_, c_;
            __sincosf(yaw, &s_, &c_);
            float spDT = sp * DT;
            x   = fmaf(spDT, c_, x);
            y   = fmaf(spDT, s_, y);
            yaw = fmaf(angv, DT, yaw);
            sp  = spn;
        }

        ((float4*)ox)[k] = make_float4(outx[0], outx[1], outx[2], outx[3]);
        ((float4*)oy)[k] = make_float4(outy[0], outy[1], outy[2], outy[3]);
        ((float4*)ow)[k] = make_float4(outw[0], outw[1], outw[2], outw[3]);
        ((float4*)os)[k] = make_float4(outs[0], outs[1], outs[2], outs[3]);
    }
}

extern "C" void kernel_launch(void* const* d_in, const int* in_sizes, int n_in,
                              void* d_out, int out_size, void* d_ws, size_t ws_size,
                              hipStream_t stream) {
    const float* sx       = (const float*)d_in[0];
    const float* sy       = (const float*)d_in[1];
    const float* syaw     = (const float*)d_in[2];
    const float* ssp      = (const float*)d_in[3];
    const float* accel    = (const float*)d_in[4];
    const float* steering = (const float*)d_in[5];
    float* out = (float*)d_out;

    int B = in_sizes[0];
    dim3 block(256);
    dim3 grid((B + 255) / 256);
    hipLaunchKernelGGL(bicycle_kernel, grid, block, 0, stream,
                       sx, sy, syaw, ssp, accel, steering, out, B);
}

// Round 2
// 431.648 us; speedup vs baseline: 1.2925x; 1.2925x over previous
//
#include <hip/hip_runtime.h>

#define T 256
#define TC 16            // half-chunk staged in LDS
#define SC 32            // super-chunk: controls load granularity (128 B)
#define V 128            // vehicles (threads) per block
#define DT 0.05f
#define WHEELBASE 2.7f
#define MAX_STEER 0.5235987755982988f  // deg2rad(30)
#define MAX_SPEED 100.0f
#define FR 0.1f
#define FA 0.01f

// One thread per vehicle. States for 16 steps staged in LDS, then written out
// transposed so global stores are contiguous 64 B per 16 lanes (full sectors,
// each written exactly once -> no partial-line RMW / re-writeback).
__global__ __launch_bounds__(V) void bicycle_kernel(
    const float* __restrict__ sx, const float* __restrict__ sy,
    const float* __restrict__ syaw, const float* __restrict__ ssp,
    const float* __restrict__ accel, const float* __restrict__ steering,
    float* __restrict__ out, int B)
{
    // pad 17: sim-phase write banks (17*tid + j) % 32 -> 2-way (free);
    // writeout read banks (17*vv + j) % 32 -> ~2-way (free).
    __shared__ float lds[4][V][TC + 1];   // 34,816 B

    const int tid = threadIdx.x;
    const int b   = blockIdx.x * V + tid;

    float x   = sx[b];
    float y   = sy[b];
    float yaw = syaw[b];
    float sp  = ssp[b];

    const float4* a4 = (const float4*)(accel    + (size_t)b * T);
    const float4* s4 = (const float4*)(steering + (size_t)b * T);

    const size_t plane   = (size_t)B * T;
    const size_t vehBase = (size_t)blockIdx.x * V;

    for (int c = 0; c < T / SC; ++c) {        // 8 super-chunks of 32 steps
        // ---- load this super-chunk's controls: 128 B/thread/array, full lines
        float4 av[SC / 4], sv[SC / 4];
        #pragma unroll
        for (int i = 0; i < SC / 4; ++i) {
            av[i] = a4[c * (SC / 4) + i];
            sv[i] = s4[c * (SC / 4) + i];
        }
        float ac[SC], sc[SC];
        #pragma unroll
        for (int i = 0; i < SC / 4; ++i) {
            ac[4*i+0] = av[i].x; ac[4*i+1] = av[i].y; ac[4*i+2] = av[i].z; ac[4*i+3] = av[i].w;
            sc[4*i+0] = sv[i].x; sc[4*i+1] = sv[i].y; sc[4*i+2] = sv[i].z; sc[4*i+3] = sv[i].w;
        }

        #pragma unroll
        for (int h = 0; h < 2; ++h) {         // two half-chunks of 16 steps
            // ---- simulate 16 steps, record pre-step state into LDS
            #pragma unroll
            for (int j = 0; j < TC; ++j) {
                const int t = h * TC + j;     // compile-time after unroll
                lds[0][tid][j] = x;
                lds[1][tid][j] = y;
                lds[2][tid][j] = yaw;
                lds[3][tid][j] = sp;

                float fr    = fmaf(FA * sp, sp, sp * FR);
                float spn   = fmaf(DT, ac[t] - fr, sp);
                spn         = fminf(fmaxf(spn, 0.0f), MAX_SPEED);
                float steer = fminf(fmaxf(sc[t], -MAX_STEER), MAX_STEER);
                float angv  = sp * __tanf(steer) * (1.0f / WHEELBASE);
                float s_, c_;
                __sincosf(yaw, &s_, &c_);
                float spDT = sp * DT;
                x   = fmaf(spDT, c_, x);
                y   = fmaf(spDT, s_, y);
                yaw = fmaf(angv, DT, yaw);
                sp  = spn;
            }
            __syncthreads();

            // ---- cooperative transposed writeout
            // lane n = i*V + tid -> vehicle n/TC, time-offset n%TC:
            // 16 consecutive lanes write 64 B contiguous (2 full sectors).
            const int t0 = c * SC + h * TC;
            #pragma unroll
            for (int p = 0; p < 4; ++p) {
                float* op = out + (size_t)p * plane + vehBase * T + t0;
                #pragma unroll
                for (int i = 0; i < TC; ++i) {
                    const int n  = i * V + tid;
                    const int vv = n >> 4;    // n / TC
                    const int j  = n & 15;    // n % TC
                    op[(size_t)vv * T + j] = lds[p][vv][j];
                }
            }
            __syncthreads();
        }
    }
}

extern "C" void kernel_launch(void* const* d_in, const int* in_sizes, int n_in,
                              void* d_out, int out_size, void* d_ws, size_t ws_size,
                              hipStream_t stream) {
    const float* sx       = (const float*)d_in[0];
    const float* sy       = (const float*)d_in[1];
    const float* syaw     = (const float*)d_in[2];
    const float* ssp      = (const float*)d_in[3];
    const float* accel    = (const float*)d_in[4];
    const float* steering = (const float*)d_in[5];
    float* out = (float*)d_out;

    int B = in_sizes[0];
    dim3 block(V);
    dim3 grid(B / V);
    hipLaunchKernelGGL(bicycle_kernel, grid, block, 0, stream,
                       sx, sy, syaw, ssp, accel, steering, out, B);
}